// Round 5
// baseline (34.888 us; speedup 1.0000x reference)
//
#include <hip/hip_runtime.h>

// Ray-sphere intersection: N rays x 64 moving spheres -> closest hit distance.
// x: (1, N, 7) f32 = [origin(3), t_ray(1), direction(3)]
// z: (1, 384) f32 = 64 spheres x [center(3), velocity(3)]
// out: mu (N) ++ sigma (N), f32
//
// 4 rays/thread as two v2f groups -> v_pk_fma_f32 for all pairwise math, two
// independent dep chains for ILP, 7x dwordx4 coalesced ray loads.
// Tail: raw v_sqrt_f32 (disc<0 -> NaN -> ordered compares false -> BIG),
// then the R3-proven cmp/cndmask/fmin select. No bit-pattern tricks.

typedef float v2f __attribute__((ext_vector_type(2)));

constexpr int NSPH = 64;
constexpr float BIGF = 1e10f;

__device__ __forceinline__ void step2(
    const v2f& ox, const v2f& oy, const v2f& oz, const v2f& t,
    const v2f& dx, const v2f& dy, const v2f& dz,
    float cx, float cy, float cz, float vx, float vy, float vz,
    v2f& closest)
{
    // oc = (c - o) + v * t                       (3 pk_sub + 3 pk_fma)
    v2f ocx = __builtin_elementwise_fma((v2f){vx, vx}, t, cx - ox);
    v2f ocy = __builtin_elementwise_fma((v2f){vy, vy}, t, cy - oy);
    v2f ocz = __builtin_elementwise_fma((v2f){vz, vz}, t, cz - oz);
    // b = d . oc                                 (1 pk_mul + 2 pk_fma)
    v2f b = __builtin_elementwise_fma(dx, ocx,
            __builtin_elementwise_fma(dy, ocy, dz * ocz));
    // csq = |oc|^2                               (1 pk_mul + 2 pk_fma)
    v2f csq = __builtin_elementwise_fma(ocx, ocx,
              __builtin_elementwise_fma(ocy, ocy, ocz * ocz));
    // disc = b^2 - (csq - 1)                     (1 pk_sub + 1 pk_fma)
    v2f disc = __builtin_elementwise_fma(b, b, (v2f){1.0f, 1.0f} - csq);

    // sq = sqrt(disc); disc<0 -> NaN -> both compares below false -> BIG
    v2f sq;
    sq[0] = __builtin_amdgcn_sqrtf(disc[0]);
    sq[1] = __builtin_amdgcn_sqrtf(disc[1]);

    v2f t0 = b - sq;   // 1 pk
    v2f t1 = b + sq;   // 1 pk

    #pragma unroll
    for (int k = 0; k < 2; ++k) {
        float r1 = (t1[k] > 0.0f) ? t1[k] : BIGF;   // cmp + cndmask
        float r  = (t0[k] > 0.0f) ? t0[k] : r1;     // cmp + cndmask
        closest[k] = fminf(closest[k], r);          // v_min
    }
}

__global__ __launch_bounds__(256, 8) void ray_sphere_kernel(
    const float* __restrict__ x, const float* __restrict__ z,
    float* __restrict__ out, int N)
{
    int tid = blockIdx.x * 256 + threadIdx.x;
    long n0 = (long)tid * 4;                      // 4 rays per thread
    if (n0 >= N) return;

    // 28 consecutive floats, 16B-aligned (tid*112B) -> 7x global_load_dwordx4
    const float4* xr = (const float4*)(x + n0 * 7);
    float4 w0 = xr[0], w1 = xr[1], w2 = xr[2], w3 = xr[3],
           w4 = xr[4], w5 = xr[5], w6 = xr[6];

    // group A = rays {0,1}, group B = rays {2,3}
    v2f oxA = {w0.x, w1.w}, oyA = {w0.y, w2.x}, ozA = {w0.z, w2.y};
    v2f tA  = {w0.w, w2.z};
    v2f dxA = {w1.x, w2.w}, dyA = {w1.y, w3.x}, dzA = {w1.z, w3.y};

    v2f oxB = {w3.z, w5.y}, oyB = {w3.w, w5.z}, ozB = {w4.x, w5.w};
    v2f tB  = {w4.y, w6.x};
    v2f dxB = {w4.z, w6.y}, dyB = {w4.w, w6.z}, dzB = {w5.x, w6.w};

    // normalize d: d / (sqrt(|d|^2) + 1e-12)
    {
        v2f n2 = __builtin_elementwise_fma(dxA, dxA,
                 __builtin_elementwise_fma(dyA, dyA, dzA * dzA));
        v2f inv;
        inv[0] = __builtin_amdgcn_rcpf(__builtin_amdgcn_sqrtf(n2[0]) + 1e-12f);
        inv[1] = __builtin_amdgcn_rcpf(__builtin_amdgcn_sqrtf(n2[1]) + 1e-12f);
        dxA *= inv; dyA *= inv; dzA *= inv;
    }
    {
        v2f n2 = __builtin_elementwise_fma(dxB, dxB,
                 __builtin_elementwise_fma(dyB, dyB, dzB * dzB));
        v2f inv;
        inv[0] = __builtin_amdgcn_rcpf(__builtin_amdgcn_sqrtf(n2[0]) + 1e-12f);
        inv[1] = __builtin_amdgcn_rcpf(__builtin_amdgcn_sqrtf(n2[1]) + 1e-12f);
        dxB *= inv; dyB *= inv; dzB *= inv;
    }

    v2f closestA = {BIGF, BIGF};
    v2f closestB = {BIGF, BIGF};

    #pragma unroll 8
    for (int s = 0; s < NSPH; ++s) {
        const float* zs = z + s * 6;   // uniform -> s_load, SGPR broadcast
        float cx = zs[0], cy = zs[1], cz = zs[2];
        float vx = zs[3], vy = zs[4], vz = zs[5];
        step2(oxA, oyA, ozA, tA, dxA, dyA, dzA, cx, cy, cz, vx, vy, vz, closestA);
        step2(oxB, oyB, ozB, tB, dxB, dyB, dzB, cx, cy, cz, vx, vy, vz, closestB);
    }

    float4 mu;
    mu.x = closestA[0];
    mu.y = closestA[1];
    mu.z = closestB[0];
    mu.w = closestB[1];
    *(float4*)(out + n0) = mu;
    *(float4*)(out + N + n0) = make_float4(0.002f, 0.002f, 0.002f, 0.002f);
}

extern "C" void kernel_launch(void* const* d_in, const int* in_sizes, int n_in,
                              void* d_out, int out_size, void* d_ws, size_t ws_size,
                              hipStream_t stream) {
    const float* x = (const float*)d_in[0];
    const float* z = (const float*)d_in[1];
    float* out = (float*)d_out;
    int N = in_sizes[0] / 7;   // 1048576

    int threads = N / 4;
    int blocks = (threads + 255) / 256;
    ray_sphere_kernel<<<blocks, 256, 0, stream>>>(x, z, out, N);
}

// Round 6
// 34.821 us; speedup vs baseline: 1.0019x; 1.0019x over previous
//
#include <hip/hip_runtime.h>

// Ray-sphere intersection: N rays x 64 moving spheres -> closest hit distance.
// x: (1, N, 7) f32 = [origin(3), t_ray(1), direction(3)]
// z: (1, 384) f32 = 64 spheres x [center(3), velocity(3)]
// out: mu (N) ++ sigma (N), f32
//
// 4 rays/thread as two v2f groups -> v_pk_fma_f32 for all pairwise math, two
// independent dep chains for ILP, 7x dwordx4 coalesced ray loads.
// Tail: raw v_sqrt_f32 (disc<0 -> NaN -> ordered compares false -> BIG),
// then cmp/cndmask/fmin select.
//
// FROZEN ARITHMETIC (correctness-proven in R3/R5): disc = fma(b,b, 1.0f-csq)
// with csq the plain |oc|^2 chain. R4 showed that changing disc's rounding by
// ~1 ulp flips a tangent-boundary pair vs the reference (one flip = 1e10 error).
// Do not re-associate oc/b/csq/disc.
//
// This round's single change: __launch_bounds__(256,4) (was (256,8)). Grid is
// only 1024 blocks = 4 waves/SIMD of work; the (256,8) bound strangled the
// allocator to 24 VGPRs and serialized the two chains (VALUBusy 56%).

typedef float v2f __attribute__((ext_vector_type(2)));

constexpr int NSPH = 64;
constexpr float BIGF = 1e10f;

__device__ __forceinline__ void step2(
    const v2f& ox, const v2f& oy, const v2f& oz, const v2f& t,
    const v2f& dx, const v2f& dy, const v2f& dz,
    float cx, float cy, float cz, float vx, float vy, float vz,
    v2f& closest)
{
    // oc = (c - o) + v * t                       (3 pk_sub + 3 pk_fma)
    v2f ocx = __builtin_elementwise_fma((v2f){vx, vx}, t, cx - ox);
    v2f ocy = __builtin_elementwise_fma((v2f){vy, vy}, t, cy - oy);
    v2f ocz = __builtin_elementwise_fma((v2f){vz, vz}, t, cz - oz);
    // b = d . oc                                 (1 pk_mul + 2 pk_fma)
    v2f b = __builtin_elementwise_fma(dx, ocx,
            __builtin_elementwise_fma(dy, ocy, dz * ocz));
    // csq = |oc|^2                               (1 pk_mul + 2 pk_fma)
    v2f csq = __builtin_elementwise_fma(ocx, ocx,
              __builtin_elementwise_fma(ocy, ocy, ocz * ocz));
    // disc = b^2 + (1 - csq)                     (1 pk_sub + 1 pk_fma) FROZEN
    v2f disc = __builtin_elementwise_fma(b, b, (v2f){1.0f, 1.0f} - csq);

    // sq = sqrt(disc); disc<0 -> NaN -> both compares below false -> BIG
    v2f sq;
    sq[0] = __builtin_amdgcn_sqrtf(disc[0]);
    sq[1] = __builtin_amdgcn_sqrtf(disc[1]);

    v2f t0 = b - sq;   // 1 pk
    v2f t1 = b + sq;   // 1 pk

    #pragma unroll
    for (int k = 0; k < 2; ++k) {
        float r1 = (t1[k] > 0.0f) ? t1[k] : BIGF;   // cmp + cndmask
        float r  = (t0[k] > 0.0f) ? t0[k] : r1;     // cmp + cndmask
        closest[k] = fminf(closest[k], r);          // v_min
    }
}

__global__ __launch_bounds__(256, 4) void ray_sphere_kernel(
    const float* __restrict__ x, const float* __restrict__ z,
    float* __restrict__ out, int N)
{
    int tid = blockIdx.x * 256 + threadIdx.x;
    long n0 = (long)tid * 4;                      // 4 rays per thread
    if (n0 >= N) return;

    // 28 consecutive floats, 16B-aligned (tid*112B) -> 7x global_load_dwordx4
    const float4* xr = (const float4*)(x + n0 * 7);
    float4 w0 = xr[0], w1 = xr[1], w2 = xr[2], w3 = xr[3],
           w4 = xr[4], w5 = xr[5], w6 = xr[6];

    // group A = rays {0,1}, group B = rays {2,3}
    v2f oxA = {w0.x, w1.w}, oyA = {w0.y, w2.x}, ozA = {w0.z, w2.y};
    v2f tA  = {w0.w, w2.z};
    v2f dxA = {w1.x, w2.w}, dyA = {w1.y, w3.x}, dzA = {w1.z, w3.y};

    v2f oxB = {w3.z, w5.y}, oyB = {w3.w, w5.z}, ozB = {w4.x, w5.w};
    v2f tB  = {w4.y, w6.x};
    v2f dxB = {w4.z, w6.y}, dyB = {w4.w, w6.z}, dzB = {w5.x, w6.w};

    // normalize d: d / (sqrt(|d|^2) + 1e-12)
    {
        v2f n2 = __builtin_elementwise_fma(dxA, dxA,
                 __builtin_elementwise_fma(dyA, dyA, dzA * dzA));
        v2f inv;
        inv[0] = __builtin_amdgcn_rcpf(__builtin_amdgcn_sqrtf(n2[0]) + 1e-12f);
        inv[1] = __builtin_amdgcn_rcpf(__builtin_amdgcn_sqrtf(n2[1]) + 1e-12f);
        dxA *= inv; dyA *= inv; dzA *= inv;
    }
    {
        v2f n2 = __builtin_elementwise_fma(dxB, dxB,
                 __builtin_elementwise_fma(dyB, dyB, dzB * dzB));
        v2f inv;
        inv[0] = __builtin_amdgcn_rcpf(__builtin_amdgcn_sqrtf(n2[0]) + 1e-12f);
        inv[1] = __builtin_amdgcn_rcpf(__builtin_amdgcn_sqrtf(n2[1]) + 1e-12f);
        dxB *= inv; dyB *= inv; dzB *= inv;
    }

    v2f closestA = {BIGF, BIGF};
    v2f closestB = {BIGF, BIGF};

    #pragma unroll 16
    for (int s = 0; s < NSPH; ++s) {
        const float* zs = z + s * 6;   // uniform -> s_load, SGPR broadcast
        float cx = zs[0], cy = zs[1], cz = zs[2];
        float vx = zs[3], vy = zs[4], vz = zs[5];
        step2(oxA, oyA, ozA, tA, dxA, dyA, dzA, cx, cy, cz, vx, vy, vz, closestA);
        step2(oxB, oyB, ozB, tB, dxB, dyB, dzB, cx, cy, cz, vx, vy, vz, closestB);
    }

    float4 mu;
    mu.x = closestA[0];
    mu.y = closestA[1];
    mu.z = closestB[0];
    mu.w = closestB[1];
    *(float4*)(out + n0) = mu;
    *(float4*)(out + N + n0) = make_float4(0.002f, 0.002f, 0.002f, 0.002f);
}

extern "C" void kernel_launch(void* const* d_in, const int* in_sizes, int n_in,
                              void* d_out, int out_size, void* d_ws, size_t ws_size,
                              hipStream_t stream) {
    const float* x = (const float*)d_in[0];
    const float* z = (const float*)d_in[1];
    float* out = (float*)d_out;
    int N = in_sizes[0] / 7;   // 1048576

    int threads = N / 4;
    int blocks = (threads + 255) / 256;
    ray_sphere_kernel<<<blocks, 256, 0, stream>>>(x, z, out, N);
}

// Round 8
// 34.330 us; speedup vs baseline: 1.0162x; 1.0143x over previous
//
#include <hip/hip_runtime.h>

// Ray-sphere intersection: N rays x 64 moving spheres -> closest hit distance.
// x: (1, N, 7) f32 = [origin(3), t_ray(1), direction(3)]
// z: (1, 384) f32 = 64 spheres x [center(3), velocity(3)]
// out: mu (N) ++ sigma (N), f32
//
// 2 rays/thread, v2f -> v_pk_fma_f32 core, raw v_sqrt_f32 NaN path,
// R5-proven cmp/cndmask/fmin select tail. (Unsigned-bit-min tail is BANNED:
// failed R4 and R7 with hit-where-ref-says-miss outputs; select tail proven.)
//
// FROZEN ARITHMETIC (R3/R5/R6-proven): oc/b/csq chains, normalize, and
// disc = fma(b,b, 1.0f - csq). 1-ulp re-associations flip tangent-boundary
// pairs vs the reference (one flip = 1e10 error). Do not touch.
//
// New this round: per-block sphere-phase stagger. All waves previously ran
// the identical unrolled code and stalled on the same sphere s_load batches
// in lockstep (idle time ~14us, invariant to occupancy 16->32 waves/CU).
// Block b starts at sphere (b&7)*8 and wraps; min-reduction is order-
// invariant so the result set is bit-identical. 8 groups x 8 spheres keeps
// each group's index range affine off a runtime SGPR base (s_load_dwordx16
// batchable), and 8 blocks/CU give all 8 phases per CU.

typedef float v2f __attribute__((ext_vector_type(2)));

constexpr float BIGF = 1e10f;

__global__ __launch_bounds__(256, 8) void ray_sphere_kernel(
    const float* __restrict__ x, const float* __restrict__ z,
    float* __restrict__ out, int N)
{
    int tid = blockIdx.x * 256 + threadIdx.x;
    long n0 = (long)tid * 2;                      // 2 rays per thread
    if (n0 >= N) return;

    // 14 consecutive floats, 8B-aligned (tid*56B) -> 7x global_load_dwordx2
    const float2* xr = (const float2*)(x + n0 * 7);
    float2 w0 = xr[0], w1 = xr[1], w2 = xr[2], w3 = xr[3],
           w4 = xr[4], w5 = xr[5], w6 = xr[6];

    v2f ox = {w0.x, w3.y}, oy = {w0.y, w4.x}, oz = {w1.x, w4.y};
    v2f t  = {w1.y, w5.x};
    v2f dx = {w2.x, w5.y}, dy = {w2.y, w6.x}, dz = {w3.x, w6.y};

    // normalize d: d / (sqrt(|d|^2) + 1e-12)   (FROZEN)
    {
        v2f n2 = __builtin_elementwise_fma(dx, dx,
                 __builtin_elementwise_fma(dy, dy, dz * dz));
        v2f inv;
        inv[0] = __builtin_amdgcn_rcpf(__builtin_amdgcn_sqrtf(n2[0]) + 1e-12f);
        inv[1] = __builtin_amdgcn_rcpf(__builtin_amdgcn_sqrtf(n2[1]) + 1e-12f);
        dx *= inv; dy *= inv; dz *= inv;
    }

    v2f closest = {BIGF, BIGF};

    int s0 = (blockIdx.x & 7) << 3;   // block phase: sphere start 0,8,...,56

    #pragma unroll
    for (int j = 0; j < 8; ++j) {
        // group base: runtime SGPR, affine inner range -> batched s_loads
        const float* zg = z + ((s0 + (j << 3)) & 63) * 6;
        #pragma unroll
        for (int k = 0; k < 8; ++k) {
            const float* zs = zg + k * 6;
            float cx = zs[0], cy = zs[1], cz = zs[2];
            float vx = zs[3], vy = zs[4], vz = zs[5];

            // oc = (c - o) + v * t               (FROZEN)
            v2f ocx = __builtin_elementwise_fma((v2f){vx, vx}, t, cx - ox);
            v2f ocy = __builtin_elementwise_fma((v2f){vy, vy}, t, cy - oy);
            v2f ocz = __builtin_elementwise_fma((v2f){vz, vz}, t, cz - oz);
            // b = d . oc                         (FROZEN)
            v2f b = __builtin_elementwise_fma(dx, ocx,
                    __builtin_elementwise_fma(dy, ocy, dz * ocz));
            // csq = |oc|^2                       (FROZEN)
            v2f csq = __builtin_elementwise_fma(ocx, ocx,
                      __builtin_elementwise_fma(ocy, ocy, ocz * ocz));
            // disc = b^2 + (1 - csq)             (FROZEN)
            v2f disc = __builtin_elementwise_fma(b, b, (v2f){1.0f, 1.0f} - csq);

            // disc<0 -> NaN -> both compares below false -> BIG
            v2f sq;
            sq[0] = __builtin_amdgcn_sqrtf(disc[0]);
            sq[1] = __builtin_amdgcn_sqrtf(disc[1]);

            v2f t0 = b - sq;
            v2f t1 = b + sq;

            #pragma unroll
            for (int kk = 0; kk < 2; ++kk) {
                float r1 = (t1[kk] > 0.0f) ? t1[kk] : BIGF;   // cmp + cndmask
                float r  = (t0[kk] > 0.0f) ? t0[kk] : r1;     // cmp + cndmask
                closest[kk] = fminf(closest[kk], r);          // v_min
            }
        }
    }

    *(float2*)(out + n0) = make_float2(closest[0], closest[1]);
    *(float2*)(out + N + n0) = make_float2(0.002f, 0.002f);
}

extern "C" void kernel_launch(void* const* d_in, const int* in_sizes, int n_in,
                              void* d_out, int out_size, void* d_ws, size_t ws_size,
                              hipStream_t stream) {
    const float* x = (const float*)d_in[0];
    const float* z = (const float*)d_in[1];
    float* out = (float*)d_out;
    int N = in_sizes[0] / 7;   // 1048576

    int threads = N / 2;
    int blocks = (threads + 255) / 256;   // 2048
    ray_sphere_kernel<<<blocks, 256, 0, stream>>>(x, z, out, N);
}